// Round 7
// baseline (88.605 us; speedup 1.0000x reference)
//
#include <hip/hip_runtime.h>
#include <hip/hip_bf16.h>

typedef unsigned short u16;
typedef __attribute__((ext_vector_type(8))) __bf16 bf16x8;
typedef __attribute__((ext_vector_type(4))) float f32x4;

#define B_SZ 4096
#define D_SZ 1024
#define MARGIN 0.2f

__device__ __forceinline__ u16 f2bf(float x) {
  __hip_bfloat16 h = __float2bfloat16(x);
  u16 r; __builtin_memcpy(&r, &h, 2); return r;
}

// ---------------- normalize + cast to bf16 + diag ----------------
__global__ void norm_diag_kernel(const float* __restrict__ im,
                                 const float* __restrict__ tx,
                                 u16* __restrict__ imn,
                                 u16* __restrict__ txn,
                                 float* __restrict__ diag) {
  const int row = blockIdx.x;
  const int t = threadIdx.x;
  const size_t base = (size_t)row * D_SZ;
  float4 vi = reinterpret_cast<const float4*>(im + base)[t];
  float4 vt = reinterpret_cast<const float4*>(tx + base)[t];
  float ssi = vi.x * vi.x + vi.y * vi.y + vi.z * vi.z + vi.w * vi.w;
  float sst = vt.x * vt.x + vt.y * vt.y + vt.z * vt.z + vt.w * vt.w;
  float dot = vi.x * vt.x + vi.y * vt.y + vi.z * vt.z + vi.w * vt.w;
#pragma unroll
  for (int off = 32; off > 0; off >>= 1) {
    ssi += __shfl_down(ssi, off, 64);
    sst += __shfl_down(sst, off, 64);
    dot += __shfl_down(dot, off, 64);
  }
  __shared__ float w[3][4];
  if ((t & 63) == 0) { int wi = t >> 6; w[0][wi] = ssi; w[1][wi] = sst; w[2][wi] = dot; }
  __syncthreads();
  const float tssi = (w[0][0] + w[0][1]) + (w[0][2] + w[0][3]);
  const float tsst = (w[1][0] + w[1][1]) + (w[1][2] + w[1][3]);
  const float tdot = (w[2][0] + w[2][1]) + (w[2][2] + w[2][3]);
  const float si = 1.0f / fmaxf(sqrtf(tssi), 1e-12f);
  const float st = 1.0f / fmaxf(sqrtf(tsst), 1e-12f);
  u16 oi[4] = { f2bf(vi.x * si), f2bf(vi.y * si), f2bf(vi.z * si), f2bf(vi.w * si) };
  u16 ot[4] = { f2bf(vt.x * st), f2bf(vt.y * st), f2bf(vt.z * st), f2bf(vt.w * st) };
  ushort4 pi, pt; __builtin_memcpy(&pi, oi, 8); __builtin_memcpy(&pt, ot, 8);
  reinterpret_cast<ushort4*>(imn + base)[t] = pi;
  reinterpret_cast<ushort4*>(txn + base)[t] = pt;
  if (t == 0) diag[row] = tdot * si * st;
}

// ---------------- 256x256 snake-pipelined GEMM + fused loss ----------------
// Round-7: r6's conflict-free layout (128B-pitch regions + XOR swizzle, 0
// conflicts measured) + minimum LDS reads (24/wave/K-tile via snake quadrant
// order with persistent A/B register sets) + one-phase-ahead read issue so
// ds_read drain overlaps MFMA. 1 barrier/phase (4/K-tile). Counted lgkm
// waits + sched_barrier(0) (rule #18). Stage stream Q1:SB01(t+1) Q2:SA0(t+2)
// Q3:SB23(t+2) Q4:SA1(t+2); single vmcnt(4) gate per K-tile at Q4.
__device__ __forceinline__ void gload_lds16(const u16* g, u16* l) {
  __builtin_amdgcn_global_load_lds((__attribute__((address_space(1))) void*)g,
                                   (__attribute__((address_space(3))) void*)l,
                                   16, 0, 0);
}

#define BAR() __builtin_amdgcn_s_barrier()
#define WAITDS(n) do { asm volatile("s_waitcnt lgkmcnt(" #n ")" ::: "memory"); \
                       __builtin_amdgcn_sched_barrier(0); } while (0)
#define VMC(n) asm volatile("s_waitcnt vmcnt(" #n ")" ::: "memory")

__global__ __launch_bounds__(512, 2) void gemm_loss_kernel(
    const u16* __restrict__ A,   // imn [4096][1024]
    const u16* __restrict__ Bt,  // txn [4096][1024]
    const float* __restrict__ diag,
    float* __restrict__ sim,     // d_out+1, row-major [4096][4096]
    float* __restrict__ loss) {
  __shared__ u16 sm[65536];      // 8 regions x [128 rows][64 cols]

  const int tid = threadIdx.x;
  const int l = tid & 63;
  const int w = tid >> 6;
  const int wr = w >> 2;         // 0..1  M half
  const int wc = w & 3;          // 0..3  N quarter
  const int ar = l & 15;
  const int arh = l >> 4;

  const int bid = blockIdx.x;
  const int s = (bid & 7) * 32 + (bid >> 3);
  const int tm = (s >> 4) * 256;
  const int tn = (s & 15) * 256;

  f32x4 acc[8][4] = {};

  // ---- staging (pre-swizzled global source; LDS dest linear) ----
  const int l3 = l >> 3;
  const int cb = (l & 7) ^ l3;            // involution with read swizzle
  const int rho = w * 16 + l3;            // chunk-0 region row
  const u16* pA[2]; const u16* pB[2];
  pA[0] = A + (size_t)(tm + (rho >> 6) * 128 + (rho & 63)) * D_SZ + cb * 8;
  pA[1] = A + (size_t)(tm + (rho >> 6) * 128 + 64 + (rho & 63)) * D_SZ + cb * 8;
  pB[0] = Bt + (size_t)(tn + (rho >> 5) * 64 + (rho & 31)) * D_SZ + cb * 8;
  pB[1] = Bt + (size_t)(tn + (rho >> 5) * 64 + 32 + (rho & 31)) * D_SZ + cb * 8;

  auto SA = [&](int kt, int buf, int mg) {   // stage A region (2 loads/wave)
    u16* d = sm + (buf * 4 + mg) * 8192 + w * 1024;
    const u16* g = pA[mg] + kt * 64;
    gload_lds16(g, d);
    gload_lds16(g + 8 * D_SZ, d + 512);
  };
  auto SB = [&](int kt, int buf, int half) { // stage B region (half0=n01)
    u16* d = sm + (buf * 4 + 2 + half) * 8192 + w * 1024;
    const u16* g = pB[half] + kt * 64;
    gload_lds16(g, d);
    gload_lds16(g + 8 * D_SZ, d + 512);
  };

  // ---- reads (swizzled slot = nominal ^ (row&7); row&7 == ar&7) ----
  const int sl0 = (arh ^ (ar & 7)) * 8;
  const int sl1 = ((4 + arh) ^ (ar & 7)) * 8;
  const int aOfs = (wr * 64 + ar) * 64;
  const int bOfs = (wc * 32 + ar) * 64;

  bf16x8 aE[4][2], aO[4][2], bA[2][2], bB[2][2];
  auto RDA = [&](bf16x8 (&dst)[4][2], int buf, int mg) {    // 8 ds_read_b128
    const u16* base = sm + (buf * 4 + mg) * 8192 + aOfs;
#pragma unroll
    for (int m = 0; m < 4; m++) {
      dst[m][0] = *(const bf16x8*)&base[m * 1024 + sl0];
      dst[m][1] = *(const bf16x8*)&base[m * 1024 + sl1];
    }
  };
  auto RDB = [&](bf16x8 (&dst)[2][2], int buf, int half) {  // 4 ds_read_b128
    const u16* base = sm + (buf * 4 + 2 + half) * 8192 + bOfs;
#pragma unroll
    for (int n = 0; n < 2; n++) {
      dst[n][0] = *(const bf16x8*)&base[n * 1024 + sl0];
      dst[n][1] = *(const bf16x8*)&base[n * 1024 + sl1];
    }
  };
  auto MM = [&](bf16x8 (&aS)[4][2], bf16x8 (&bS)[2][2], int mb, int nb) {
    __builtin_amdgcn_s_setprio(1);
#pragma unroll
    for (int m = 0; m < 4; m++)
#pragma unroll
      for (int n = 0; n < 2; n++) {
        acc[mb + m][nb + n] = __builtin_amdgcn_mfma_f32_16x16x32_bf16(
            aS[m][0], bS[n][0], acc[mb + m][nb + n], 0, 0, 0);
        acc[mb + m][nb + n] = __builtin_amdgcn_mfma_f32_16x16x32_bf16(
            aS[m][1], bS[n][1], acc[mb + m][nb + n], 0, 0, 0);
      }
    __builtin_amdgcn_s_setprio(0);
  };

  // ---- prologue (steady-state stage order), then first operand reads ----
  SA(0, 0, 0); SB(0, 0, 1); SA(0, 0, 1); SB(0, 0, 0);
  SA(1, 1, 0); SB(1, 1, 1); SA(1, 1, 1);
  VMC(0);
  BAR();
  RDA(aE, 0, 0); RDB(bA, 0, 0);          // a0(0), b01(0)

  // ---- main loop: 7 iters x 2 K-tiles (tiles 0..13) ----
#pragma unroll 1
  for (int i = 0; i < 7; ++i) {
    const int te = 2 * i, to = 2 * i + 1;
    // even tile: b01 in bA, b23 in bB; aE = a0, aO = a1
    RDB(bB, 0, 1); SB(to, 1, 0);     WAITDS(4);  MM(aE, bA, 0, 0); BAR();
    RDA(aO, 0, 1); SA(te + 2, 0, 0); WAITDS(8);  MM(aE, bB, 0, 2); BAR();
    SB(te + 2, 0, 1);                WAITDS(0);  MM(aO, bB, 4, 2); BAR();
    VMC(4);
    RDA(aE, 1, 0); RDB(bB, 1, 0); SA(te + 2, 0, 1);
                                     WAITDS(12); MM(aO, bA, 4, 0); BAR();
    // odd tile: b01 in bB, b23 in bA
    RDB(bA, 1, 1); SB(te + 2, 0, 0); WAITDS(4);  MM(aE, bB, 0, 0); BAR();
    RDA(aO, 1, 1); SA(to + 2, 1, 0); WAITDS(8);  MM(aE, bA, 0, 2); BAR();
    SB(to + 2, 1, 1);                WAITDS(0);  MM(aO, bA, 4, 2); BAR();
    VMC(4);
    RDA(aE, 0, 0); RDB(bA, 0, 0); SA(to + 2, 1, 1);
                                     WAITDS(12); MM(aO, bB, 4, 0); BAR();
  }

  // ---- tail: tile 14 (even role) ----
  RDB(bB, 0, 1); SB(15, 1, 0); WAITDS(4);  MM(aE, bA, 0, 0); BAR();
  RDA(aO, 0, 1);               WAITDS(8);  MM(aE, bB, 0, 2); BAR();
                               WAITDS(0);  MM(aO, bB, 4, 2); BAR();
  VMC(0);
  RDA(aE, 1, 0); RDB(bB, 1, 0); WAITDS(12); MM(aO, bA, 4, 0); BAR();
  // ---- tail: tile 15 (odd role) ----
  RDB(bA, 1, 1); WAITDS(4);  MM(aE, bB, 0, 0); BAR();
  RDA(aO, 1, 1); WAITDS(8);  MM(aE, bA, 0, 2); BAR();
                 WAITDS(0);  MM(aO, bA, 4, 2); BAR();
                 WAITDS(0);  MM(aO, bB, 4, 0);

  // ---- C-write + hinge loss ----
  float dcs[4];
#pragma unroll
  for (int n = 0; n < 4; n++) dcs[n] = diag[tn + wc * 64 + n * 16 + ar];
  float lsum = 0.f;
#pragma unroll
  for (int m = 0; m < 8; m++) {
#pragma unroll
    for (int i = 0; i < 4; i++) {
      const int r = tm + wr * 128 + m * 16 + arh * 4 + i;
      const float dr = diag[r];
#pragma unroll
      for (int n = 0; n < 4; n++) {
        const int c = tn + wc * 64 + n * 16 + ar;
        const float s_ = acc[m][n][i];
        sim[(size_t)r * B_SZ + c] = s_;
        if (r != c)
          lsum += fmaxf(MARGIN + s_ - dr, 0.f) + fmaxf(MARGIN + s_ - dcs[n], 0.f);
      }
    }
  }
#pragma unroll
  for (int off = 32; off > 0; off >>= 1) lsum += __shfl_down(lsum, off, 64);
  if (l == 0) atomicAdd(loss, lsum);
}

extern "C" void kernel_launch(void* const* d_in, const int* in_sizes, int n_in,
                              void* d_out, int out_size, void* d_ws, size_t ws_size,
                              hipStream_t stream) {
  const float* im = (const float*)d_in[0];
  const float* tx = (const float*)d_in[1];
  float* out = (float*)d_out;
  float* loss = out;        // output 0: scalar total_loss
  float* sim = out + 1;     // output 1: [4096][4096]

  u16* imn = (u16*)d_ws;
  u16* txn = imn + (size_t)B_SZ * D_SZ;
  float* diag = (float*)(txn + (size_t)B_SZ * D_SZ);

  hipMemsetAsync(d_out, 0, sizeof(float), stream);
  norm_diag_kernel<<<B_SZ, 256, 0, stream>>>(im, tx, imn, txn, diag);
  gemm_loss_kernel<<<(B_SZ / 256) * (B_SZ / 256), 512, 0, stream>>>(imn, txn, diag, sim, loss);
}